// Round 13
// baseline (279.105 us; speedup 1.0000x reference)
//
#include <hip/hip_runtime.h>
#include <hip/hip_bf16.h>
#include <stdint.h>

// ---------------------------------------------------------------------------
// RG-LRU block: T=8192, D_MODEL=768, D_RNN=1024, KW=4.
// Round 17: residency push to 6 blocks/CU for the bf16 dense GEMMs.
// Evidence: depth (R12) null; cadence null on small-K; the ONLY lever that
// moved small-K GEMMs in 12 rounds was blocks/CU.  gemm1 at occ 40% is
// capped exactly by launch_bounds(4) + 32KB arena.  This round:
//  - bf16-EPI GEMMs: 16KB arena (dbuf-2 A ring 2x8KB = epilogue tile 16KB),
//    __launch_bounds__(256,6) -> 6 blocks/CU, 24 waves (75% occ target).
//  - K-loop = R11-verified dbuf-2 / jit-B / vmcnt(2) form (R12 ring reverted).
//  - EPI==0 (fp32 out) keeps 32KB arena @ 4 blocks.
//  - conv (R8), scans, prep byte-identical to R11/R12.
// ---------------------------------------------------------------------------

#define T_LEN 8192
#define DM 768
#define DR 1024
#define NC 128   // scan chunks
#define CL 64    // chunk length

typedef __bf16 bf16x8 __attribute__((ext_vector_type(8)));
typedef float  f32x4  __attribute__((ext_vector_type(4)));

#define AS1 __attribute__((address_space(1)))
#define AS3 __attribute__((address_space(3)))

__device__ __forceinline__ void cp16_g2l(const void* g, void* l) {
    __builtin_amdgcn_global_load_lds((const AS1 void*)g, (AS3 void*)l, 16, 0, 0);
}

__device__ __forceinline__ float gelu_tanh(float x) {
    const float inner = 0.7978845608028654f * (x + 0.044715f * x * x * x);
    return 0.5f * x * (1.f + tanhf(inner));
}

__device__ __forceinline__ __bf16 f2b(float v) {
    __hip_bfloat16 h = __float2bfloat16(v);
    return *reinterpret_cast<__bf16*>(&h);
}

// ---------------------------------------------------------------------------
// Dense GEMM, BN=64, residency-first: C[m,n] = sum_k A[m,k]*B[n,k] (+bias).
// BM=128, BK=32, 256 threads (4 waves, 2Mx2N over 128x64).
// EPI!=0: 16KB arena, 6 blocks/CU (24 waves).  EPI==0: 32KB arena, 4 blocks.
// A: LDS dbuf [2][128*32] (8KB/slot); 32-wide rows = 4 chunks; slot s of
//    row r holds global chunk s ^ ((r>>1)&3) (R4-proven scheme).
// B: fragment-major WF [ntile][kt][lane][16B]; NI=2 frags jit to regs.
// Per iter t: loadB(t) -> stageA(t+1) -> vmcnt(2) -> barrier ->
//             4 ds_read + 8 MFMA -> barrier.   K % 32 == 0.  (R11-verified)
// EPI: 0 = fp32 +bias; 1 = bf16 +bias; 2 = split (gelu->Cv / D2 rows+3).
// ---------------------------------------------------------------------------
template<int EPI>
__global__ __launch_bounds__(256, EPI == 0 ? 4 : 6)
void gemm_mfma(const __hip_bfloat16* __restrict__ A,
               const __hip_bfloat16* __restrict__ WF,
               const float* __restrict__ bias,
               void* __restrict__ Cv,
               int K, int lda, int N,
               __hip_bfloat16* __restrict__ D2)
{
    __shared__ __align__(16) unsigned char smem[EPI == 0 ? 32768 : 16384];
    __bf16* Asb = (__bf16*)smem;           // [2][128*32] = 16KB

    const int tid  = threadIdx.x;
    const int lane = tid & 63;
    const int wave = tid >> 6;
    const size_t m0 = (size_t)blockIdx.x * 128;
    const int    n0 = blockIdx.y * 64;
    const int wm = (wave >> 1) * 64;
    const int wn = (wave & 1) * 32;

    f32x4 acc[4][2];
#pragma unroll
    for (int i = 0; i < 4; ++i)
#pragma unroll
        for (int j = 0; j < 2; ++j)
            acc[i][j] = f32x4{0.f, 0.f, 0.f, 0.f};

    const int frow = lane & 15;
    const int fq   = lane >> 4;             // chunk index 0..3 in 32-wide row
    const int NKT  = K >> 5;                // 32-col k-steps

    // per-lane base into fragment-major weights: ntile_base = (n0+wn)/16
    const __bf16* wbase = (const __bf16*)WF +
        (((size_t)((n0 + wn) >> 4) * NKT) << 9) + (lane << 3);

    auto stageA = [&](int buf, int k0) {   // 128 rows x 4 chunks = 512 chunks
#pragma unroll
        for (int q = 0; q < 2; ++q) {
            const int lin = q * 256 + tid;
            const int rr  = lin >> 2;
            const int gc  = (lin & 3) ^ ((rr >> 1) & 3);
            cp16_g2l(A + (m0 + rr) * (size_t)lda + k0 + gc * 8,
                     Asb + buf * 4096 + lin * 8);
        }
    };

    stageA(0, 0);
#pragma unroll 1
    for (int t = 0; t < NKT; ++t) {
        bf16x8 bfr[2];
#pragma unroll
        for (int ni = 0; ni < 2; ++ni)
            bfr[ni] = *(const bf16x8*)(wbase +
                (((size_t)(ni * NKT + t)) << 9));
        if (t + 1 < NKT) {
            stageA((t + 1) & 1, (t + 1) * 32);
            // leave only the 2 just-issued next-A cp16s in flight; this
            // iter's A (oldest) and B (middle) must be complete.
            asm volatile("s_waitcnt vmcnt(2)" ::: "memory");
        } else {
            asm volatile("s_waitcnt vmcnt(0)" ::: "memory");
        }
        __builtin_amdgcn_sched_barrier(0);
        __builtin_amdgcn_s_barrier();          // A[t&1] staged for all waves
        __builtin_amdgcn_sched_barrier(0);

        const int ab = (t & 1) * 4096;
        bf16x8 af[4];
#pragma unroll
        for (int mi = 0; mi < 4; ++mi) {
            const int R = wm + mi * 16 + frow;
            af[mi] = *(const bf16x8*)&Asb[ab + R * 32 + ((fq ^ ((R >> 1) & 3)) * 8)];
        }
        asm volatile("s_waitcnt lgkmcnt(0)" ::: "memory");
        __builtin_amdgcn_sched_barrier(0);
        __builtin_amdgcn_s_setprio(1);
#pragma unroll
        for (int mi = 0; mi < 4; ++mi)
#pragma unroll
            for (int ni = 0; ni < 2; ++ni)
                acc[mi][ni] = __builtin_amdgcn_mfma_f32_16x16x32_bf16(
                    af[mi], bfr[ni], acc[mi][ni], 0, 0, 0);
        __builtin_amdgcn_s_setprio(0);
        __builtin_amdgcn_sched_barrier(0);
        __builtin_amdgcn_s_barrier();          // A[t&1] free for overwrite
        __builtin_amdgcn_sched_barrier(0);
    }

    // ---- epilogue: acc -> swizzled LDS -> coalesced 16B/lane global stores.
    // C/D frag layout: col = lane&15, row = (lane>>4)*4 + reg.
    __syncthreads();
    const int er = fq * 4;
    const int ec = frow;

    if (EPI == 0) {
        // fp32 tile 128 x 64: 32 KB arena.
        float* Cl = (float*)smem;
#pragma unroll
        for (int ni = 0; ni < 2; ++ni) {
            const int cc = wn + ni * 16 + ec;
            const float bv = bias ? bias[n0 + cc] : 0.f;
#pragma unroll
            for (int mi = 0; mi < 4; ++mi)
#pragma unroll
                for (int r2 = 0; r2 < 4; ++r2) {
                    const int R = wm + mi * 16 + er + r2;
                    Cl[R * 64 + ((((cc >> 2) ^ (R & 7)) << 2) | (cc & 3))] =
                        acc[mi][ni][r2] + bv;
                }
        }
        __syncthreads();
        float* outp = (float*)Cv;
#pragma unroll
        for (int p = 0; p < 8; ++p) {
            const int R   = (tid >> 4) + p * 16;
            const int chn = tid & 15;
            const f32x4 v = *(const f32x4*)&Cl[R * 64 + ((chn ^ (R & 7)) << 2)];
            *(f32x4*)&outp[(m0 + R) * (size_t)N + n0 + chn * 4] = v;
        }
    } else {
        // bf16 tile 128 x 64 = 16 KB arena.
        __bf16* Cl = (__bf16*)smem;
        const bool ahalf = (EPI == 2) && (n0 < 1024);   // block-uniform
#pragma unroll
        for (int ni = 0; ni < 2; ++ni) {
            const int cc = wn + ni * 16 + ec;
            const float bv = bias ? bias[n0 + cc] : 0.f;
#pragma unroll
            for (int mi = 0; mi < 4; ++mi)
#pragma unroll
                for (int r2 = 0; r2 < 4; ++r2) {
                    const int R = wm + mi * 16 + er + r2;
                    float v = acc[mi][ni][r2] + bv;
                    if (EPI == 2 && ahalf) v = gelu_tanh(v);
                    Cl[R * 64 + ((((cc >> 3) ^ (R & 7)) << 3) | (cc & 7))] = f2b(v);
                }
        }
        __syncthreads();
#pragma unroll
        for (int p = 0; p < 4; ++p) {
            const int R   = (tid >> 3) + p * 32;
            const int chn = tid & 7;
            const bf16x8 v = *(const bf16x8*)&Cl[R * 64 + ((chn ^ (R & 7)) << 3)];
            if (EPI == 1) {
                *(bf16x8*)((__bf16*)Cv + (m0 + R) * (size_t)N + n0 + chn * 8) = v;
            } else if (n0 < 1024) {
                *(bf16x8*)((__bf16*)Cv + (m0 + R) * 1024 + n0 + chn * 8) = v;
            } else {
                *(bf16x8*)((__bf16*)D2 + (m0 + R + 3) * 1024 + (n0 - 1024) + chn * 8) = v;
            }
        }
    }
}

// ---------------------------------------------------------------------------
// Conv (byte-identical to R8): B-frags global->register, A-halo LDS dbuf,
// 64 MFMA/wave per barrier-pair, 2 blocks/CU.
// ---------------------------------------------------------------------------
__global__ __launch_bounds__(256, 2)
void conv_mfma(const __hip_bfloat16* __restrict__ bbp,
               const __hip_bfloat16* __restrict__ WB,
               __hip_bfloat16* __restrict__ C)
{
    __shared__ __align__(16) unsigned char smem[32768];
    __bf16* Ah = (__bf16*)smem;             // [2][132*32] halo dbuf (16.9KB)

    const int tid  = threadIdx.x;
    const int lane = tid & 63;
    const int wave = tid >> 6;
    const size_t m0 = (size_t)blockIdx.x * 128;
    const int    n0 = blockIdx.y * 128;
    const int wm = (wave >> 1) * 64;
    const int wn = (wave & 1) * 64;

    f32x4 acc[4][4];
#pragma unroll
    for (int i = 0; i < 4; ++i)
#pragma unroll
        for (int j = 0; j < 4; ++j)
            acc[i][j] = f32x4{0.f, 0.f, 0.f, 0.f};

    const int frow = lane & 15;
    const int fq   = lane >> 4;

    const __bf16* wbase = (const __bf16*)WB +
        ((size_t)((n0 + wn) >> 4) << 16) + (lane << 3);

    auto loadB = [&](bf16x8 (&b)[4][4], int t1) {
#pragma unroll
        for (int s = 0; s < 4; ++s)
#pragma unroll
            for (int ni = 0; ni < 4; ++ni)
                b[s][ni] = *(const bf16x8*)(wbase + ((size_t)ni << 16) +
                                            t1 * 2048 + s * 512);
    };
    auto stageA = [&](int abuf, int kc) {   // 132 rows x 4 chunks = 528 chunks
#pragma unroll
        for (int q = 0; q < 2; ++q) {
            const int lin = q * 256 + tid;
            const int rr  = lin >> 2;
            const int gc  = (lin & 3) ^ ((rr >> 1) & 3);
            cp16_g2l(bbp + (m0 + rr) * 1024 + kc + gc * 8, Ah + abuf * 4224 + lin * 8);
        }
        if (tid < 16) {
            const int lin = 512 + tid;
            const int rr  = lin >> 2;
            const int gc  = (lin & 3) ^ ((rr >> 1) & 3);
            cp16_g2l(bbp + (m0 + rr) * 1024 + kc + gc * 8, Ah + abuf * 4224 + lin * 8);
        }
    };

    bf16x8 bA[4][4], bB[4][4];
    stageA(0, 0);
    loadB(bA, 0);

    auto iter = [&](bf16x8 (&bCur)[4][4], bf16x8 (&bNxt)[4][4], int t) {
        if (t + 1 < 32) {
            loadB(bNxt, t + 1);
            asm volatile("s_waitcnt vmcnt(16)" ::: "memory");
        } else {
            asm volatile("s_waitcnt vmcnt(0)" ::: "memory");
        }
        __builtin_amdgcn_sched_barrier(0);
        __builtin_amdgcn_s_barrier();          // halo[t&1] staged for all waves
        __builtin_amdgcn_sched_barrier(0);

        const int ab = (t & 1) * 4224;
        __builtin_amdgcn_s_setprio(1);
#pragma unroll
        for (int s = 0; s < 4; ++s) {
            bf16x8 af[4];
#pragma unroll
            for (int mi = 0; mi < 4; ++mi) {
                const int R = wm + mi * 16 + frow + s;       // shifted halo row
                af[mi] = *(const bf16x8*)&Ah[ab + R * 32 + ((fq ^ ((R >> 1) & 3)) * 8)];
            }
#pragma unroll
            for (int mi = 0; mi < 4; ++mi)
#pragma unroll
                for (int ni = 0; ni < 4; ++ni)
                    acc[mi][ni] = __builtin_amdgcn_mfma_f32_16x16x32_bf16(
                        af[mi], bCur[s][ni], acc[mi][ni], 0, 0, 0);
        }
        __builtin_amdgcn_s_setprio(0);
        __builtin_amdgcn_sched_barrier(0);
        __builtin_amdgcn_s_barrier();          // halo[t&1] free for overwrite
        __builtin_amdgcn_sched_barrier(0);
        if (t + 1 < 32) stageA((t + 1) & 1, (t + 1) * 32);
    };

#pragma unroll 1
    for (int tp = 0; tp < 16; ++tp) {
        iter(bA, bB, 2 * tp);
        iter(bB, bA, 2 * tp + 1);
    }

    // ---- epilogue: bf16 tile 128x128 via swizzled LDS, coalesced stores.
    __syncthreads();
    const int er = fq * 4;
    const int ec = frow;
    __bf16* Cl = (__bf16*)smem;
#pragma unroll
    for (int ni = 0; ni < 4; ++ni) {
        const int cc = wn + ni * 16 + ec;
#pragma unroll
        for (int mi = 0; mi < 4; ++mi)
#pragma unroll
            for (int r2 = 0; r2 < 4; ++r2) {
                const int R = wm + mi * 16 + er + r2;
                Cl[R * 128 + ((((cc >> 3) ^ (R & 7)) << 3) | (cc & 7))] =
                    f2b(acc[mi][ni][r2]);
            }
    }
    __syncthreads();
#pragma unroll
    for (int p = 0; p < 8; ++p) {
        const int R   = (tid >> 4) + p * 16;
        const int chn = tid & 15;
        const bf16x8 v = *(const bf16x8*)&Cl[R * 128 + ((chn ^ (R & 7)) << 3)];
        *(bf16x8*)((__bf16*)C + (m0 + R) * 1024 + n0 + chn * 8) = v;
    }
}

// One prep kernel (byte-identical to R11).  w1/w_rg/w_out in FRAGMENT-MAJOR
// [ntile][kt][lane][8]: lane(fq*16+frow) of frag (nt,kt) holds
// W[nt*16+frow][kt*32+fq*8+j0].  conv WB layout + bbp pad unchanged.
#define PREP_X   6291456            // 8192*768
#define PREP_W1  (PREP_X + 1572864) // + 2048*768
#define PREP_WRG (PREP_W1 + 2097152)// + 2048*1024
#define PREP_WO  (PREP_WRG + 786432)// + 768*1024
#define PREP_CW  (PREP_WO + 4194304)// + 1024*4096
#define PREP_TOT (PREP_CW + 3072)   // + pad rows
__global__ void prep_kernel(const float* __restrict__ x, const float* __restrict__ w1,
                            const float* __restrict__ w_rg, const float* __restrict__ w_out,
                            const float* __restrict__ conv_w,
                            __hip_bfloat16* __restrict__ xb, __hip_bfloat16* __restrict__ w1f,
                            __hip_bfloat16* __restrict__ w_rgf, __hip_bfloat16* __restrict__ w_outf,
                            __hip_bfloat16* __restrict__ wbigb, __hip_bfloat16* __restrict__ bbp)
{
    const int idx = blockIdx.x * 256 + threadIdx.x;
    if (idx < PREP_X) {
        xb[idx] = __float2bfloat16(x[idx]);
    } else if (idx < PREP_W1) {
        // w1f: K=768, NKT=24, ntile block = 24*512 = 12288 elements
        const int i  = idx - PREP_X;
        const int nti = i / 12288;
        const int r  = i % 12288;
        const int kt = r >> 9;
        const int r2 = r & 511;
        const int l  = r2 >> 3, j0 = r2 & 7;
        const int row = nti * 16 + (l & 15);
        const int col = kt * 32 + (l >> 4) * 8 + j0;
        w1f[i] = __float2bfloat16(w1[row * 768 + col]);
    } else if (idx < PREP_WRG) {
        // w_rgf: K=1024, NKT=32, ntile block = 16384 elements
        const int i  = idx - PREP_W1;
        const int nti = i >> 14;
        const int r  = i & 16383;
        const int kt = r >> 9;
        const int r2 = r & 511;
        const int l  = r2 >> 3, j0 = r2 & 7;
        const int row = nti * 16 + (l & 15);
        const int col = kt * 32 + (l >> 4) * 8 + j0;
        w_rgf[i] = __float2bfloat16(w_rg[row * 1024 + col]);
    } else if (idx < PREP_WO) {
        // w_outf: 768 rows, K=1024, NKT=32
        const int i  = idx - PREP_WRG;
        const int nti = i >> 14;
        const int r  = i & 16383;
        const int kt = r >> 9;
        const int r2 = r & 511;
        const int l  = r2 >> 3, j0 = r2 & 7;
        const int row = nti * 16 + (l & 15);
        const int col = kt * 32 + (l >> 4) * 8 + j0;
        w_outf[i] = __float2bfloat16(w_out[row * 1024 + col]);
    } else if (idx < PREP_CW) {
        // fragment-major conv weights: WB[nt][kcI][s][lane][8 bf16]
        const int n    = idx - PREP_WO;
        const int nti  = n >> 16;
        const int r1   = n & 65535;
        const int kcI  = r1 >> 11;
        const int r2   = r1 & 2047;
        const int s    = r2 >> 9;
        const int r3   = r2 & 511;
        const int l    = r3 >> 3;
        const int j0   = r3 & 7;
        const int frow = l & 15, fq = l >> 4;
        const int o = nti * 16 + frow;
        const int i = kcI * 32 + fq * 8 + j0;
        wbigb[n] = __float2bfloat16(conv_w[o * 4096 + i * 4 + s]);
    } else {
        bbp[idx - PREP_CW] = __float2bfloat16(0.f);
    }
}

// Gates recomputed inline from g_pre (T x 2048 bf16) + bc (bf16):
__global__ void scan_pass1(const __hip_bfloat16* __restrict__ gp,
                           const __hip_bfloat16* __restrict__ bc,
                           const float* __restrict__ Lambda,
                           float* __restrict__ ch, float* __restrict__ ca)
{
    const int c = blockIdx.y * 256 + threadIdx.x;
    const int j = blockIdx.x;
    const float cl = -8.f * log1pf(expf(Lambda[c]));
    float h = 0.f, ap = 1.f;
    const int t0 = j * CL;
    for (int tt = 0; tt < CL; ++tt) {
        const int t = t0 + tt;
        const long gi = (long)t * 2048 + c;
        const float ig = 1.f / (1.f + expf(-__bfloat162float(gp[gi])));
        const float rg = 1.f / (1.f + expf(-__bfloat162float(gp[gi + 1024])));
        const float a  = expf(cl * rg);
        const float gx = sqrtf(fmaxf(0.f, 1.f - a * a)) * ig *
                         __bfloat162float(bc[(long)t * 1024 + c]);
        h  = fmaf(a, h, gx);
        ap *= a;
    }
    ch[j * 1024 + c] = h;
    ca[j * 1024 + c] = ap;
}

__global__ void scan_combine(float* __restrict__ ch, const float* __restrict__ ca)
{
    const int c = blockIdx.x * 256 + threadIdx.x;
    float carry = 0.f;
    for (int j = 0; j < NC; ++j) {
        const float hj = ch[j * 1024 + c];
        const float aj = ca[j * 1024 + c];
        ch[j * 1024 + c] = carry;
        carry = fmaf(aj, carry, hj);
    }
}

// Rescan with carry; z = ab * y -> bf16 (zb aliases bc: same-element RMW per thread).
__global__ void scan_pass2(const __hip_bfloat16* __restrict__ gp, const __hip_bfloat16* bc,
                           const float* __restrict__ Lambda,
                           const float* __restrict__ carry_in,
                           const __hip_bfloat16* __restrict__ ab,
                           __hip_bfloat16* zb)
{
    const int c = blockIdx.y * 256 + threadIdx.x;
    const int j = blockIdx.x;
    const float cl = -8.f * log1pf(expf(Lambda[c]));
    float h = carry_in[j * 1024 + c];
    const int t0 = j * CL;
    for (int tt = 0; tt < CL; ++tt) {
        const int t = t0 + tt;
        const long gi = (long)t * 2048 + c;
        const long bi = (long)t * 1024 + c;
        const float ig = 1.f / (1.f + expf(-__bfloat162float(gp[gi])));
        const float rg = 1.f / (1.f + expf(-__bfloat162float(gp[gi + 1024])));
        const float a  = expf(cl * rg);
        const float gx = sqrtf(fmaxf(0.f, 1.f - a * a)) * ig * __bfloat162float(bc[bi]);
        h = fmaf(a, h, gx);
        zb[bi] = __float2bfloat16(__bfloat162float(ab[bi]) * h);
    }
}

extern "C" void kernel_launch(void* const* d_in, const int* in_sizes, int n_in,
                              void* d_out, int out_size, void* d_ws, size_t ws_size,
                              hipStream_t stream)
{
    const float* x      = (const float*)d_in[0];
    const float* w1     = (const float*)d_in[1];
    const float* b1     = (const float*)d_in[2];
    const float* conv_w = (const float*)d_in[3];
    const float* w_rg   = (const float*)d_in[4];
    const float* b_rg   = (const float*)d_in[5];
    const float* w_out  = (const float*)d_in[6];
    const float* b_out  = (const float*)d_in[7];
    const float* Lambda = (const float*)d_in[8];
    float* out = (float*)d_out;
    (void)in_sizes; (void)n_in; (void)out_size; (void)ws_size;

    // ---- workspace layout (~110 MB) ----
    char* p = (char*)d_ws;
    auto alloc = [&](size_t bytes) { char* r = p; p += (bytes + 255) & ~255ULL; return r; };
    __hip_bfloat16* gpre  = (__hip_bfloat16*)alloc(8192ULL * 2048 * 2); // 32 MB
    __hip_bfloat16* ab    = (__hip_bfloat16*)alloc(8192ULL * 1024 * 2); // 16 MB
    __hip_bfloat16* bbp   = (__hip_bfloat16*)alloc(8200ULL * 1024 * 2); // 16.8 MB
    __hip_bfloat16* bcb   = (__hip_bfloat16*)alloc(8192ULL * 1024 * 2); // 16 MB (later zb)
    __hip_bfloat16* wbigb = (__hip_bfloat16*)alloc(1024ULL * 4096 * 2); // 8 MB
    __hip_bfloat16* xb    = (__hip_bfloat16*)alloc(8192ULL * 768 * 2);  // 12 MB
    __hip_bfloat16* w1f   = (__hip_bfloat16*)alloc(2048ULL * 768 * 2);  // 3 MB (frag-major)
    __hip_bfloat16* w_rgf = (__hip_bfloat16*)alloc(2048ULL * 1024 * 2); // 4 MB (frag-major)
    __hip_bfloat16* w_outf= (__hip_bfloat16*)alloc(768ULL * 1024 * 2);  // 1.5 MB (frag-major)
    float*          chv   = (float*)alloc(NC * 1024ULL * 4);
    float*          cav   = (float*)alloc(NC * 1024ULL * 4);
    __hip_bfloat16* zb    = bcb;   // overlay

    prep_kernel<<<PREP_TOT / 256, 256, 0, stream>>>(x, w1, w_rg, w_out, conv_w,
                                                    xb, w1f, w_rgf, w_outf, wbigb, bbp);

    // h = x @ w1.T + b1, fused split: ab = bf16(gelu), bbp = bf16 (rows +3)
    {
        dim3 grid(T_LEN / 128, 2048 / 64);
        gemm_mfma<2><<<grid, 256, 0, stream>>>(xb, w1f, b1, ab, DM, DM, 2048, bbp);
    }

    // bc = causal conv (B-frags global->reg from fragment-major WB) -> bf16
    {
        dim3 grid(T_LEN / 128, 1024 / 128);
        conv_mfma<<<grid, 256, 0, stream>>>(bbp, wbigb, bcb);
    }

    // g_pre = bc @ w_rg.T + b_rg -> bf16
    {
        dim3 grid(T_LEN / 128, 2048 / 64);
        gemm_mfma<1><<<grid, 256, 0, stream>>>(bcb, w_rgf, b_rg, gpre, DR, DR, 2048, nullptr);
    }

    // chunked scan with fused gates; z = ab*y -> bf16 (overlays bcb)
    {
        dim3 gs(NC, DR / 256);
        scan_pass1<<<gs, 256, 0, stream>>>(gpre, bcb, Lambda, chv, cav);
        scan_combine<<<DR / 256, 256, 0, stream>>>(chv, cav);
        scan_pass2<<<gs, 256, 0, stream>>>(gpre, bcb, Lambda, chv, ab, zb);
    }

    // out = z @ w_out.T + b_out -> fp32
    {
        dim3 grid(T_LEN / 128, DM / 64);
        gemm_mfma<0><<<grid, 256, 0, stream>>>(zb, w_outf, b_out, out, DR, DR, DM, nullptr);
    }
}

// Round 14
// 271.759 us; speedup vs baseline: 1.0270x; 1.0270x over previous
//
#include <hip/hip_runtime.h>
#include <hip/hip_bf16.h>
#include <stdint.h>

// ---------------------------------------------------------------------------
// RG-LRU block: T=8192, D_MODEL=768, D_RNN=1024, KW=4.
// Round 18: algebraic conv fusion.  bc = conv(w1b @ x) = (conv_w (*) w1b) @ x
// = sum_s V_s @ x[t+s-3], V = conv_w (*) w1b precomputed ON DEVICE (6.4 GFLOP
// GEMM through the same template).  Effects:
//  - gemm1 halves (N=1024, gelu half only; b_branch never materialized)
//  - conv K 4096 -> 3072 (convx from x directly, 3-row zero-padded xbp)
//  - bbp intermediate (16MB write + re-read) deleted
// Pipeline: prep1 -> Vgemm -> repack_v -> gemm1 -> convx -> gemm3 -> scans
// -> out.  gemm template (R13), conv structure (R8), scans unchanged.
// ---------------------------------------------------------------------------

#define T_LEN 8192
#define DM 768
#define DR 1024
#define NC 128   // scan chunks
#define CL 64    // chunk length

typedef __bf16 bf16x8 __attribute__((ext_vector_type(8)));
typedef float  f32x4  __attribute__((ext_vector_type(4)));

#define AS1 __attribute__((address_space(1)))
#define AS3 __attribute__((address_space(3)))

__device__ __forceinline__ void cp16_g2l(const void* g, void* l) {
    __builtin_amdgcn_global_load_lds((const AS1 void*)g, (AS3 void*)l, 16, 0, 0);
}

__device__ __forceinline__ float gelu_tanh(float x) {
    const float inner = 0.7978845608028654f * (x + 0.044715f * x * x * x);
    return 0.5f * x * (1.f + tanhf(inner));
}

__device__ __forceinline__ __bf16 f2b(float v) {
    __hip_bfloat16 h = __float2bfloat16(v);
    return *reinterpret_cast<__bf16*>(&h);
}

// ---------------------------------------------------------------------------
// Dense GEMM (R13-verified), BN=64: C[m,n] = sum_k A[m,k]*B[n,k] (+bias).
// BM=128, BK=32, 256 threads (4 waves, 2Mx2N over 128x64).
// EPI!=0: 16KB arena, 6 blocks/CU.  EPI==0: 32KB arena, 4 blocks.
// A: LDS dbuf [2][128*32]; slot s of row r holds chunk s ^ ((r>>1)&3).
// B: fragment-major WF [ntile][kt][lane][16B]; NI=2 frags jit to regs.
// EPI: 0 = fp32 +bias; 1 = bf16 +bias; 2 = bf16 gelu (stride-1024 out).
// ---------------------------------------------------------------------------
template<int EPI>
__global__ __launch_bounds__(256, EPI == 0 ? 4 : 6)
void gemm_mfma(const __hip_bfloat16* __restrict__ A,
               const __hip_bfloat16* __restrict__ WF,
               const float* __restrict__ bias,
               void* __restrict__ Cv,
               int K, int lda, int N,
               __hip_bfloat16* __restrict__ D2)
{
    __shared__ __align__(16) unsigned char smem[EPI == 0 ? 32768 : 16384];
    __bf16* Asb = (__bf16*)smem;           // [2][128*32] = 16KB

    const int tid  = threadIdx.x;
    const int lane = tid & 63;
    const int wave = tid >> 6;
    const size_t m0 = (size_t)blockIdx.x * 128;
    const int    n0 = blockIdx.y * 64;
    const int wm = (wave >> 1) * 64;
    const int wn = (wave & 1) * 32;

    f32x4 acc[4][2];
#pragma unroll
    for (int i = 0; i < 4; ++i)
#pragma unroll
        for (int j = 0; j < 2; ++j)
            acc[i][j] = f32x4{0.f, 0.f, 0.f, 0.f};

    const int frow = lane & 15;
    const int fq   = lane >> 4;             // chunk index 0..3 in 32-wide row
    const int NKT  = K >> 5;                // 32-col k-steps

    const __bf16* wbase = (const __bf16*)WF +
        (((size_t)((n0 + wn) >> 4) * NKT) << 9) + (lane << 3);

    auto stageA = [&](int buf, int k0) {   // 128 rows x 4 chunks = 512 chunks
#pragma unroll
        for (int q = 0; q < 2; ++q) {
            const int lin = q * 256 + tid;
            const int rr  = lin >> 2;
            const int gc  = (lin & 3) ^ ((rr >> 1) & 3);
            cp16_g2l(A + (m0 + rr) * (size_t)lda + k0 + gc * 8,
                     Asb + buf * 4096 + lin * 8);
        }
    };

    stageA(0, 0);
#pragma unroll 1
    for (int t = 0; t < NKT; ++t) {
        bf16x8 bfr[2];
#pragma unroll
        for (int ni = 0; ni < 2; ++ni)
            bfr[ni] = *(const bf16x8*)(wbase +
                (((size_t)(ni * NKT + t)) << 9));
        if (t + 1 < NKT) {
            stageA((t + 1) & 1, (t + 1) * 32);
            asm volatile("s_waitcnt vmcnt(2)" ::: "memory");
        } else {
            asm volatile("s_waitcnt vmcnt(0)" ::: "memory");
        }
        __builtin_amdgcn_sched_barrier(0);
        __builtin_amdgcn_s_barrier();          // A[t&1] staged for all waves
        __builtin_amdgcn_sched_barrier(0);

        const int ab = (t & 1) * 4096;
        bf16x8 af[4];
#pragma unroll
        for (int mi = 0; mi < 4; ++mi) {
            const int R = wm + mi * 16 + frow;
            af[mi] = *(const bf16x8*)&Asb[ab + R * 32 + ((fq ^ ((R >> 1) & 3)) * 8)];
        }
        asm volatile("s_waitcnt lgkmcnt(0)" ::: "memory");
        __builtin_amdgcn_sched_barrier(0);
        __builtin_amdgcn_s_setprio(1);
#pragma unroll
        for (int mi = 0; mi < 4; ++mi)
#pragma unroll
            for (int ni = 0; ni < 2; ++ni)
                acc[mi][ni] = __builtin_amdgcn_mfma_f32_16x16x32_bf16(
                    af[mi], bfr[ni], acc[mi][ni], 0, 0, 0);
        __builtin_amdgcn_s_setprio(0);
        __builtin_amdgcn_sched_barrier(0);
        __builtin_amdgcn_s_barrier();          // A[t&1] free for overwrite
        __builtin_amdgcn_sched_barrier(0);
    }

    // ---- epilogue: acc -> swizzled LDS -> coalesced 16B/lane global stores.
    __syncthreads();
    const int er = fq * 4;
    const int ec = frow;

    if (EPI == 0) {
        float* Cl = (float*)smem;
#pragma unroll
        for (int ni = 0; ni < 2; ++ni) {
            const int cc = wn + ni * 16 + ec;
            const float bv = bias ? bias[n0 + cc] : 0.f;
#pragma unroll
            for (int mi = 0; mi < 4; ++mi)
#pragma unroll
                for (int r2 = 0; r2 < 4; ++r2) {
                    const int R = wm + mi * 16 + er + r2;
                    Cl[R * 64 + ((((cc >> 2) ^ (R & 7)) << 2) | (cc & 3))] =
                        acc[mi][ni][r2] + bv;
                }
        }
        __syncthreads();
        float* outp = (float*)Cv;
#pragma unroll
        for (int p = 0; p < 8; ++p) {
            const int R   = (tid >> 4) + p * 16;
            const int chn = tid & 15;
            const f32x4 v = *(const f32x4*)&Cl[R * 64 + ((chn ^ (R & 7)) << 2)];
            *(f32x4*)&outp[(m0 + R) * (size_t)N + n0 + chn * 4] = v;
        }
    } else {
        __bf16* Cl = (__bf16*)smem;
#pragma unroll
        for (int ni = 0; ni < 2; ++ni) {
            const int cc = wn + ni * 16 + ec;
            const float bv = bias ? bias[n0 + cc] : 0.f;
#pragma unroll
            for (int mi = 0; mi < 4; ++mi)
#pragma unroll
                for (int r2 = 0; r2 < 4; ++r2) {
                    const int R = wm + mi * 16 + er + r2;
                    float v = acc[mi][ni][r2] + bv;
                    if (EPI == 2) v = gelu_tanh(v);
                    Cl[R * 64 + ((((cc >> 3) ^ (R & 7)) << 3) | (cc & 7))] = f2b(v);
                }
        }
        __syncthreads();
#pragma unroll
        for (int p = 0; p < 4; ++p) {
            const int R   = (tid >> 3) + p * 32;
            const int chn = tid & 7;
            const bf16x8 v = *(const bf16x8*)&Cl[R * 64 + ((chn ^ (R & 7)) << 3)];
            if (EPI == 1) {
                *(bf16x8*)((__bf16*)Cv + (m0 + R) * (size_t)N + n0 + chn * 8) = v;
            } else {
                *(bf16x8*)((__bf16*)Cv + (m0 + R) * 1024 + n0 + chn * 8) = v;
            }
        }
    }
    (void)D2;
}

// ---------------------------------------------------------------------------
// convx: bc[t,o] = sum_s sum_j V[s][o][j] * xbp[t+s][j]   (xbp = x padded +3)
// R8 conv structure, K=768 per shift (24 k-iters): B-frags global->register
// from fragment-major WBf [nt][kcI<24][s][lane][8] (49152 elem/ntile);
// A-halo (132 x 32) LDS dbuf from xbp (lda=768); 64 MFMA/wave per
// barrier-pair; vmcnt(16); 2 blocks/CU.
// ---------------------------------------------------------------------------
__global__ __launch_bounds__(256, 2)
void convx_mfma(const __hip_bfloat16* __restrict__ xbp,
                const __hip_bfloat16* __restrict__ WBf,
                __hip_bfloat16* __restrict__ C)
{
    __shared__ __align__(16) unsigned char smem[32768];
    __bf16* Ah = (__bf16*)smem;             // [2][132*32] halo dbuf (16.9KB)

    const int tid  = threadIdx.x;
    const int lane = tid & 63;
    const int wave = tid >> 6;
    const size_t m0 = (size_t)blockIdx.x * 128;
    const int    n0 = blockIdx.y * 128;
    const int wm = (wave >> 1) * 64;
    const int wn = (wave & 1) * 64;

    f32x4 acc[4][4];
#pragma unroll
    for (int i = 0; i < 4; ++i)
#pragma unroll
        for (int j = 0; j < 4; ++j)
            acc[i][j] = f32x4{0.f, 0.f, 0.f, 0.f};

    const int frow = lane & 15;
    const int fq   = lane >> 4;

    const __bf16* wbase = (const __bf16*)WBf +
        (size_t)((n0 + wn) >> 4) * 49152 + (lane << 3);

    auto loadB = [&](bf16x8 (&b)[4][4], int t1) {
#pragma unroll
        for (int s = 0; s < 4; ++s)
#pragma unroll
            for (int ni = 0; ni < 4; ++ni)
                b[s][ni] = *(const bf16x8*)(wbase + (size_t)ni * 49152 +
                                            t1 * 2048 + s * 512);
    };
    auto stageA = [&](int abuf, int kc) {   // 132 rows x 4 chunks = 528 chunks
#pragma unroll
        for (int q = 0; q < 2; ++q) {
            const int lin = q * 256 + tid;
            const int rr  = lin >> 2;
            const int gc  = (lin & 3) ^ ((rr >> 1) & 3);
            cp16_g2l(xbp + (m0 + rr) * 768 + kc + gc * 8, Ah + abuf * 4224 + lin * 8);
        }
        if (tid < 16) {
            const int lin = 512 + tid;
            const int rr  = lin >> 2;
            const int gc  = (lin & 3) ^ ((rr >> 1) & 3);
            cp16_g2l(xbp + (m0 + rr) * 768 + kc + gc * 8, Ah + abuf * 4224 + lin * 8);
        }
    };

    bf16x8 bA[4][4], bB[4][4];
    stageA(0, 0);
    loadB(bA, 0);

    auto iter = [&](bf16x8 (&bCur)[4][4], bf16x8 (&bNxt)[4][4], int t) {
        if (t + 1 < 24) {
            loadB(bNxt, t + 1);
            asm volatile("s_waitcnt vmcnt(16)" ::: "memory");
        } else {
            asm volatile("s_waitcnt vmcnt(0)" ::: "memory");
        }
        __builtin_amdgcn_sched_barrier(0);
        __builtin_amdgcn_s_barrier();          // halo[t&1] staged for all waves
        __builtin_amdgcn_sched_barrier(0);

        const int ab = (t & 1) * 4224;
        __builtin_amdgcn_s_setprio(1);
#pragma unroll
        for (int s = 0; s < 4; ++s) {
            bf16x8 af[4];
#pragma unroll
            for (int mi = 0; mi < 4; ++mi) {
                const int R = wm + mi * 16 + frow + s;       // shifted halo row
                af[mi] = *(const bf16x8*)&Ah[ab + R * 32 + ((fq ^ ((R >> 1) & 3)) * 8)];
            }
#pragma unroll
            for (int mi = 0; mi < 4; ++mi)
#pragma unroll
                for (int ni = 0; ni < 4; ++ni)
                    acc[mi][ni] = __builtin_amdgcn_mfma_f32_16x16x32_bf16(
                        af[mi], bCur[s][ni], acc[mi][ni], 0, 0, 0);
        }
        __builtin_amdgcn_s_setprio(0);
        __builtin_amdgcn_sched_barrier(0);
        __builtin_amdgcn_s_barrier();          // halo[t&1] free for overwrite
        __builtin_amdgcn_sched_barrier(0);
        if (t + 1 < 24) stageA((t + 1) & 1, (t + 1) * 32);
    };

#pragma unroll 1
    for (int tp = 0; tp < 12; ++tp) {
        iter(bA, bB, 2 * tp);
        iter(bB, bA, 2 * tp + 1);
    }

    // ---- epilogue: bf16 tile 128x128 via swizzled LDS, coalesced stores.
    __syncthreads();
    const int er = fq * 4;
    const int ec = frow;
    __bf16* Cl = (__bf16*)smem;
#pragma unroll
    for (int ni = 0; ni < 4; ++ni) {
        const int cc = wn + ni * 16 + ec;
#pragma unroll
        for (int mi = 0; mi < 4; ++mi)
#pragma unroll
            for (int r2 = 0; r2 < 4; ++r2) {
                const int R = wm + mi * 16 + er + r2;
                Cl[R * 128 + ((((cc >> 3) ^ (R & 7)) << 3) | (cc & 7))] =
                    f2b(acc[mi][ni][r2]);
            }
    }
    __syncthreads();
#pragma unroll
    for (int p = 0; p < 8; ++p) {
        const int R   = (tid >> 4) + p * 16;
        const int chn = tid & 15;
        const bf16x8 v = *(const bf16x8*)&Cl[R * 128 + ((chn ^ (R & 7)) << 3)];
        *(bf16x8*)((__bf16*)C + (m0 + R) * 1024 + n0 + chn * 8) = v;
    }
}

// ---------------------------------------------------------------------------
// prep1: xbp (x bf16, 3 zero rows at top) + w1f (gelu half, frag-major) +
// w1bT (B for Vgemm: B[j][i]=w1[1024+i][j], frag-major) + cwr (A for Vgemm:
// cwr[s*1024+o][i]=conv_w[o][i][s]) + w_rgf + w_outf.
// ---------------------------------------------------------------------------
#define P_XBP  6293760              // 8195*768
#define P_W1F  (P_XBP + 786432)     // 64nt * 24kt * 512
#define P_W1BT (P_W1F + 786432)     // 48nt * 32kt * 512
#define P_CWR  (P_W1BT + 4194304)   // 4096*1024
#define P_WRG  (P_CWR + 2097152)    // 128nt * 32kt * 512
#define P_WO   (P_WRG + 786432)     // 48nt * 32kt * 512
#define P_TOT  P_WO                 // 14,944,512 = 256 * 58377
__global__ void prep1_kernel(const float* __restrict__ x, const float* __restrict__ w1,
                             const float* __restrict__ w_rg, const float* __restrict__ w_out,
                             const float* __restrict__ conv_w,
                             __hip_bfloat16* __restrict__ xbp, __hip_bfloat16* __restrict__ w1f,
                             __hip_bfloat16* __restrict__ w1bT, __hip_bfloat16* __restrict__ cwr,
                             __hip_bfloat16* __restrict__ w_rgf, __hip_bfloat16* __restrict__ w_outf)
{
    const int idx = blockIdx.x * 256 + threadIdx.x;
    if (idx < P_XBP) {
        xbp[idx] = (idx < 2304) ? __float2bfloat16(0.f)
                                : __float2bfloat16(x[idx - 2304]);
    } else if (idx < P_W1F) {
        // gelu half rows 0..1023, K=768, NKT=24
        const int i  = idx - P_XBP;
        const int nti = i / 12288;
        const int r  = i % 12288;
        const int kt = r >> 9;
        const int r2 = r & 511;
        const int l  = r2 >> 3, j0 = r2 & 7;
        const int row = nti * 16 + (l & 15);
        const int col = kt * 32 + (l >> 4) * 8 + j0;
        w1f[i] = __float2bfloat16(w1[row * 768 + col]);
    } else if (idx < P_W1BT) {
        // B for Vgemm: N=768 (j), K=1024 (i); value = w1[(1024+i)*768 + j]
        const int i  = idx - P_W1F;
        const int nti = i >> 14;            // 16384 = 32kt*512
        const int r  = i & 16383;
        const int kt = r >> 9;
        const int r2 = r & 511;
        const int l  = r2 >> 3, j0 = r2 & 7;
        const int j  = nti * 16 + (l & 15);
        const int k  = kt * 32 + (l >> 4) * 8 + j0;
        w1bT[i] = __float2bfloat16(w1[(1024 + k) * 768 + j]);
    } else if (idx < P_CWR) {
        // A for Vgemm: cwr[s*1024+o][i] = conv_w[o*4096 + i*4 + s]
        const int n   = idx - P_W1BT;
        const int row = n >> 10;
        const int i   = n & 1023;
        const int s   = row >> 10;
        const int o   = row & 1023;
        cwr[n] = __float2bfloat16(conv_w[o * 4096 + i * 4 + s]);
    } else if (idx < P_WRG) {
        // w_rgf: K=1024, NKT=32
        const int i  = idx - P_CWR;
        const int nti = i >> 14;
        const int r  = i & 16383;
        const int kt = r >> 9;
        const int r2 = r & 511;
        const int l  = r2 >> 3, j0 = r2 & 7;
        const int row = nti * 16 + (l & 15);
        const int col = kt * 32 + (l >> 4) * 8 + j0;
        w_rgf[i] = __float2bfloat16(w_rg[row * 1024 + col]);
    } else {
        // w_outf: 768 rows, K=1024, NKT=32
        const int i  = idx - P_WRG;
        const int nti = i >> 14;
        const int r  = i & 16383;
        const int kt = r >> 9;
        const int r2 = r & 511;
        const int l  = r2 >> 3, j0 = r2 & 7;
        const int row = nti * 16 + (l & 15);
        const int col = kt * 32 + (l >> 4) * 8 + j0;
        w_outf[i] = __float2bfloat16(w_out[row * 1024 + col]);
    }
}

// repack Vtmp (row-major [4096][768], rows = s*1024+o) -> conv frag-major
// WBf[nt][kcI<24][s][lane][8]: value = Vtmp[(s*1024 + nt*16+frow)*768 + j],
// j = kcI*32 + fq*8 + j0.   3,145,728 elems.
__global__ void repack_v(const __hip_bfloat16* __restrict__ Vtmp,
                         __hip_bfloat16* __restrict__ WBf)
{
    const int idx = blockIdx.x * 256 + threadIdx.x;
    const int nt  = idx / 49152;
    const int r1  = idx % 49152;
    const int kcI = r1 >> 11;
    const int r2  = r1 & 2047;
    const int s   = r2 >> 9;
    const int r3  = r2 & 511;
    const int l   = r3 >> 3;
    const int j0  = r3 & 7;
    const int o   = nt * 16 + (l & 15);
    const int j   = kcI * 32 + (l >> 4) * 8 + j0;
    WBf[idx] = Vtmp[(size_t)(s * 1024 + o) * 768 + j];
}

// Gates recomputed inline from g_pre (T x 2048 bf16) + bc (bf16):
__global__ void scan_pass1(const __hip_bfloat16* __restrict__ gp,
                           const __hip_bfloat16* __restrict__ bc,
                           const float* __restrict__ Lambda,
                           float* __restrict__ ch, float* __restrict__ ca)
{
    const int c = blockIdx.y * 256 + threadIdx.x;
    const int j = blockIdx.x;
    const float cl = -8.f * log1pf(expf(Lambda[c]));
    float h = 0.f, ap = 1.f;
    const int t0 = j * CL;
    for (int tt = 0; tt < CL; ++tt) {
        const int t = t0 + tt;
        const long gi = (long)t * 2048 + c;
        const float ig = 1.f / (1.f + expf(-__bfloat162float(gp[gi])));
        const float rg = 1.f / (1.f + expf(-__bfloat162float(gp[gi + 1024])));
        const float a  = expf(cl * rg);
        const float gx = sqrtf(fmaxf(0.f, 1.f - a * a)) * ig *
                         __bfloat162float(bc[(long)t * 1024 + c]);
        h  = fmaf(a, h, gx);
        ap *= a;
    }
    ch[j * 1024 + c] = h;
    ca[j * 1024 + c] = ap;
}

__global__ void scan_combine(float* __restrict__ ch, const float* __restrict__ ca)
{
    const int c = blockIdx.x * 256 + threadIdx.x;
    float carry = 0.f;
    for (int j = 0; j < NC; ++j) {
        const float hj = ch[j * 1024 + c];
        const float aj = ca[j * 1024 + c];
        ch[j * 1024 + c] = carry;
        carry = fmaf(aj, carry, hj);
    }
}

// Rescan with carry; z = ab * y -> bf16 (zb aliases bc: same-element RMW per thread).
__global__ void scan_pass2(const __hip_bfloat16* __restrict__ gp, const __hip_bfloat16* bc,
                           const float* __restrict__ Lambda,
                           const float* __restrict__ carry_in,
                           const __hip_bfloat16* __restrict__ ab,
                           __hip_bfloat16* zb)
{
    const int c = blockIdx.y * 256 + threadIdx.x;
    const int j = blockIdx.x;
    const float cl = -8.f * log1pf(expf(Lambda[c]));
    float h = carry_in[j * 1024 + c];
    const int t0 = j * CL;
    for (int tt = 0; tt < CL; ++tt) {
        const int t = t0 + tt;
        const long gi = (long)t * 2048 + c;
        const long bi = (long)t * 1024 + c;
        const float ig = 1.f / (1.f + expf(-__bfloat162float(gp[gi])));
        const float rg = 1.f / (1.f + expf(-__bfloat162float(gp[gi + 1024])));
        const float a  = expf(cl * rg);
        const float gx = sqrtf(fmaxf(0.f, 1.f - a * a)) * ig * __bfloat162float(bc[bi]);
        h = fmaf(a, h, gx);
        zb[bi] = __float2bfloat16(__bfloat162float(ab[bi]) * h);
    }
}

extern "C" void kernel_launch(void* const* d_in, const int* in_sizes, int n_in,
                              void* d_out, int out_size, void* d_ws, size_t ws_size,
                              hipStream_t stream)
{
    const float* x      = (const float*)d_in[0];
    const float* w1     = (const float*)d_in[1];
    const float* b1     = (const float*)d_in[2];
    const float* conv_w = (const float*)d_in[3];
    const float* w_rg   = (const float*)d_in[4];
    const float* b_rg   = (const float*)d_in[5];
    const float* w_out  = (const float*)d_in[6];
    const float* b_out  = (const float*)d_in[7];
    const float* Lambda = (const float*)d_in[8];
    float* out = (float*)d_out;
    (void)in_sizes; (void)n_in; (void)out_size; (void)ws_size;

    // ---- workspace layout (~111 MB) ----
    char* p = (char*)d_ws;
    auto alloc = [&](size_t bytes) { char* r = p; p += (bytes + 255) & ~255ULL; return r; };
    __hip_bfloat16* gpre  = (__hip_bfloat16*)alloc(8192ULL * 2048 * 2); // 32 MB
    __hip_bfloat16* ab    = (__hip_bfloat16*)alloc(8192ULL * 1024 * 2); // 16 MB
    __hip_bfloat16* xbp   = (__hip_bfloat16*)alloc(8200ULL * 768 * 2);  // 12.6 MB (3 zero + 8192 + slack)
    __hip_bfloat16* bcb   = (__hip_bfloat16*)alloc(8192ULL * 1024 * 2); // 16 MB (later zb)
    __hip_bfloat16* WBf   = (__hip_bfloat16*)alloc(1024ULL * 4 * 768 * 2); // 6.3 MB
    __hip_bfloat16* Vtmp  = (__hip_bfloat16*)alloc(4096ULL * 768 * 2);  // 6.3 MB
    __hip_bfloat16* cwr   = (__hip_bfloat16*)alloc(4096ULL * 1024 * 2); // 8.4 MB
    __hip_bfloat16* w1f   = (__hip_bfloat16*)alloc(1024ULL * 768 * 2);  // 1.5 MB
    __hip_bfloat16* w1bT  = (__hip_bfloat16*)alloc(768ULL * 1024 * 2);  // 1.5 MB
    __hip_bfloat16* w_rgf = (__hip_bfloat16*)alloc(2048ULL * 1024 * 2); // 4 MB
    __hip_bfloat16* w_outf= (__hip_bfloat16*)alloc(768ULL * 1024 * 2);  // 1.5 MB
    float*          chv   = (float*)alloc(NC * 1024ULL * 4);
    float*          cav   = (float*)alloc(NC * 1024ULL * 4);
    __hip_bfloat16* zb    = bcb;   // overlay

    prep1_kernel<<<P_TOT / 256, 256, 0, stream>>>(x, w1, w_rg, w_out, conv_w,
                                                  xbp, w1f, w1bT, cwr, w_rgf, w_outf);

    // V = conv_w (*) w1b: Vtmp[s*1024+o][j] = sum_i cwr[s*1024+o][i]*w1bT[j][i]
    {
        dim3 grid(4096 / 128, 768 / 64);
        gemm_mfma<1><<<grid, 256, 0, stream>>>(cwr, w1bT, nullptr, Vtmp, 1024, 1024, 768, nullptr);
    }
    repack_v<<<3145728 / 256, 256, 0, stream>>>(Vtmp, WBf);

    // ab = bf16(gelu(x @ w1a.T + b1a))  (gelu half only, N=1024)
    {
        dim3 grid(T_LEN / 128, 1024 / 64);
        gemm_mfma<2><<<grid, 256, 0, stream>>>(xbp + 2304, w1f, b1, ab, DM, DM, 1024, nullptr);
    }

    // bc = sum_s V_s @ x[t+s-3]  (conv directly from padded x)
    {
        dim3 grid(T_LEN / 128, 1024 / 128);
        convx_mfma<<<grid, 256, 0, stream>>>(xbp, WBf, bcb);
    }

    // g_pre = bc @ w_rg.T + b_rg -> bf16
    {
        dim3 grid(T_LEN / 128, 2048 / 64);
        gemm_mfma<1><<<grid, 256, 0, stream>>>(bcb, w_rgf, b_rg, gpre, DR, DR, 2048, nullptr);
    }

    // chunked scan with fused gates; z = ab*y -> bf16 (overlays bcb)
    {
        dim3 gs(NC, DR / 256);
        scan_pass1<<<gs, 256, 0, stream>>>(gpre, bcb, Lambda, chv, cav);
        scan_combine<<<DR / 256, 256, 0, stream>>>(chv, cav);
        scan_pass2<<<gs, 256, 0, stream>>>(gpre, bcb, Lambda, chv, ab, zb);
    }

    // out = z @ w_out.T + b_out -> fp32
    {
        dim3 grid(T_LEN / 128, DM / 64);
        gemm_mfma<0><<<grid, 256, 0, stream>>>(zb, w_outf, b_out, out, DR, DR, DM, nullptr);
    }
}

// Round 15
// 247.196 us; speedup vs baseline: 1.1291x; 1.0994x over previous
//
#include <hip/hip_runtime.h>
#include <hip/hip_bf16.h>
#include <stdint.h>

// ---------------------------------------------------------------------------
// RG-LRU block: T=8192, D_MODEL=768, D_RNN=1024, KW=4.
// Round 19 (on R14's fused-conv pipeline):
//  - dense GEMM template: BK=64 per barrier-pair (16 MFMA/wave, 2x16KB A
//    dbuf, launch_bounds(256,4)) -- the untested cadence x residency point
//    (R11/R13: 8 MFMA @ 4-6 blk; R10: 32 MFMA @ 2-3 blk reg-starved).
//  - Vgemm writes fragment-major WBf directly (EPI=3) -> repack_v + Vtmp
//    deleted.
//  - scans: NC 256 / CL 32 (2 -> 4 waves/SIMD).
//  - convx, prep1 byte-identical to R14.
// ---------------------------------------------------------------------------

#define T_LEN 8192
#define DM 768
#define DR 1024
#define NC 256   // scan chunks
#define CL 32    // chunk length

typedef __bf16 bf16x8 __attribute__((ext_vector_type(8)));
typedef float  f32x4  __attribute__((ext_vector_type(4)));

#define AS1 __attribute__((address_space(1)))
#define AS3 __attribute__((address_space(3)))

__device__ __forceinline__ void cp16_g2l(const void* g, void* l) {
    __builtin_amdgcn_global_load_lds((const AS1 void*)g, (AS3 void*)l, 16, 0, 0);
}

__device__ __forceinline__ float gelu_tanh(float x) {
    const float inner = 0.7978845608028654f * (x + 0.044715f * x * x * x);
    return 0.5f * x * (1.f + tanhf(inner));
}

__device__ __forceinline__ __bf16 f2b(float v) {
    __hip_bfloat16 h = __float2bfloat16(v);
    return *reinterpret_cast<__bf16*>(&h);
}

// ---------------------------------------------------------------------------
// Dense GEMM, BN=64, BK=64/iter: C[m,n] = sum_k A[m,k]*B[n,k] (+bias).
// BM=128, 256 threads (4 waves, 2Mx2N over 128x64), 4 blocks/CU.
// A: LDS dbuf [2][128*64] (16KB/slot); 64-wide rows = 8 chunks; slot s of
//    row r holds global chunk s ^ (r&7) (R1-verified bank-balanced scheme).
// B: fragment-major WF [ntile][kt][lane][16B]; 2 ksteps x NI=2 frags jit
//    to regs (1KB coalesced per wave load).
// Per iter t (nt = K/64): loadB(t) 4 loads -> stageA(t+1) 4 cp16 ->
//   vmcnt(4) [retires A(t)+B(t), leaves A(t+1) in flight] -> barrier ->
//   8 ds_read af -> lgkmcnt(0) -> 16 MFMA -> barrier.   K % 64 == 0.
// EPI: 0 = fp32 +bias (32KB epi tile); 1 = bf16 +bias; 2 = bf16 gelu
//      (stride-1024); 3 = bf16 -> conv frag-major WBf (Vgemm).
// ---------------------------------------------------------------------------
template<int EPI>
__global__ __launch_bounds__(256, 4)
void gemm_mfma(const __hip_bfloat16* __restrict__ A,
               const __hip_bfloat16* __restrict__ WF,
               const float* __restrict__ bias,
               void* __restrict__ Cv,
               int K, int lda, int N,
               __hip_bfloat16* __restrict__ D2)
{
    __shared__ __align__(16) unsigned char smem[32768];
    __bf16* Asb = (__bf16*)smem;           // [2][128*64] = 32KB

    const int tid  = threadIdx.x;
    const int lane = tid & 63;
    const int wave = tid >> 6;
    const size_t m0 = (size_t)blockIdx.x * 128;
    const int    n0 = blockIdx.y * 64;
    const int wm = (wave >> 1) * 64;
    const int wn = (wave & 1) * 32;

    f32x4 acc[4][2];
#pragma unroll
    for (int i = 0; i < 4; ++i)
#pragma unroll
        for (int j = 0; j < 2; ++j)
            acc[i][j] = f32x4{0.f, 0.f, 0.f, 0.f};

    const int frow = lane & 15;
    const int fq   = lane >> 4;
    const int NKT  = K >> 5;                // 32-col k-steps
    const int nt   = K >> 6;                // 64-col iterations

    // per-lane base into fragment-major weights: ntile_base = (n0+wn)/16
    const __bf16* wbase = (const __bf16*)WF +
        (((size_t)((n0 + wn) >> 4) * NKT) << 9) + (lane << 3);

    auto stageA = [&](int buf, int k0) {   // 128 rows x 8 chunks = 1024 chunks
#pragma unroll
        for (int q = 0; q < 4; ++q) {
            const int lin = q * 256 + tid;
            const int rr  = lin >> 3;
            const int gc  = (lin & 7) ^ (rr & 7);
            cp16_g2l(A + (m0 + rr) * (size_t)lda + k0 + gc * 8,
                     Asb + buf * 8192 + lin * 8);
        }
    };

    stageA(0, 0);
#pragma unroll 1
    for (int t = 0; t < nt; ++t) {
        bf16x8 bfr[2][2];
#pragma unroll
        for (int ks = 0; ks < 2; ++ks)
#pragma unroll
            for (int ni = 0; ni < 2; ++ni)
                bfr[ks][ni] = *(const bf16x8*)(wbase +
                    (((size_t)(ni * NKT + 2 * t + ks)) << 9));
        if (t + 1 < nt) {
            stageA((t + 1) & 1, (t + 1) * 64);
            // FIFO: [A(t):4][B(t):4][A(t+1):4]; vmcnt(4) retires A(t)+B(t)
            asm volatile("s_waitcnt vmcnt(4)" ::: "memory");
        } else {
            asm volatile("s_waitcnt vmcnt(0)" ::: "memory");
        }
        __builtin_amdgcn_sched_barrier(0);
        __builtin_amdgcn_s_barrier();          // A[t&1] staged for all waves
        __builtin_amdgcn_sched_barrier(0);

        const int ab = (t & 1) * 8192;
        bf16x8 af[2][4];
#pragma unroll
        for (int ks = 0; ks < 2; ++ks)
#pragma unroll
            for (int mi = 0; mi < 4; ++mi) {
                const int R = wm + mi * 16 + frow;
                af[ks][mi] = *(const bf16x8*)&Asb[ab + R * 64 +
                                                  (((ks * 4 + fq) ^ (R & 7)) * 8)];
            }
        asm volatile("s_waitcnt lgkmcnt(0)" ::: "memory");
        __builtin_amdgcn_sched_barrier(0);
        __builtin_amdgcn_s_setprio(1);
#pragma unroll
        for (int ks = 0; ks < 2; ++ks)
#pragma unroll
            for (int mi = 0; mi < 4; ++mi)
#pragma unroll
                for (int ni = 0; ni < 2; ++ni)
                    acc[mi][ni] = __builtin_amdgcn_mfma_f32_16x16x32_bf16(
                        af[ks][mi], bfr[ks][ni], acc[mi][ni], 0, 0, 0);
        __builtin_amdgcn_s_setprio(0);
        __builtin_amdgcn_sched_barrier(0);
        __builtin_amdgcn_s_barrier();          // A[t&1] free for overwrite
        __builtin_amdgcn_sched_barrier(0);
    }

    // ---- epilogue: acc -> swizzled LDS -> coalesced 16B/lane global stores.
    // C/D frag layout: col = lane&15, row = (lane>>4)*4 + reg.
    __syncthreads();
    const int er = fq * 4;
    const int ec = frow;

    if (EPI == 0) {
        // fp32 tile 128 x 64: 32 KB arena.
        float* Cl = (float*)smem;
#pragma unroll
        for (int ni = 0; ni < 2; ++ni) {
            const int cc = wn + ni * 16 + ec;
            const float bv = bias ? bias[n0 + cc] : 0.f;
#pragma unroll
            for (int mi = 0; mi < 4; ++mi)
#pragma unroll
                for (int r2 = 0; r2 < 4; ++r2) {
                    const int R = wm + mi * 16 + er + r2;
                    Cl[R * 64 + ((((cc >> 2) ^ (R & 7)) << 2) | (cc & 3))] =
                        acc[mi][ni][r2] + bv;
                }
        }
        __syncthreads();
        float* outp = (float*)Cv;
#pragma unroll
        for (int p = 0; p < 8; ++p) {
            const int R   = (tid >> 4) + p * 16;
            const int chn = tid & 15;
            const f32x4 v = *(const f32x4*)&Cl[R * 64 + ((chn ^ (R & 7)) << 2)];
            *(f32x4*)&outp[(m0 + R) * (size_t)N + n0 + chn * 4] = v;
        }
    } else {
        // bf16 tile 128 x 64 = 16 KB.
        __bf16* Cl = (__bf16*)smem;
#pragma unroll
        for (int ni = 0; ni < 2; ++ni) {
            const int cc = wn + ni * 16 + ec;
            const float bv = bias ? bias[n0 + cc] : 0.f;
#pragma unroll
            for (int mi = 0; mi < 4; ++mi)
#pragma unroll
                for (int r2 = 0; r2 < 4; ++r2) {
                    const int R = wm + mi * 16 + er + r2;
                    float v = acc[mi][ni][r2] + bv;
                    if (EPI == 2) v = gelu_tanh(v);
                    Cl[R * 64 + ((((cc >> 3) ^ (R & 7)) << 3) | (cc & 7))] = f2b(v);
                }
        }
        __syncthreads();
#pragma unroll
        for (int p = 0; p < 4; ++p) {
            const int R   = (tid >> 3) + p * 32;
            const int chn = tid & 7;
            const bf16x8 v = *(const bf16x8*)&Cl[R * 64 + ((chn ^ (R & 7)) << 3)];
            if (EPI == 1) {
                *(bf16x8*)((__bf16*)Cv + (m0 + R) * (size_t)N + n0 + chn * 8) = v;
            } else if (EPI == 2) {
                *(bf16x8*)((__bf16*)Cv + (m0 + R) * 1024 + n0 + chn * 8) = v;
            } else {
                // EPI==3: conv frag-major WBf.  m = s*1024+o, j = col.
                const int m  = (int)(m0 + R);
                const int s  = m >> 10;
                const int o  = m & 1023;
                const int j  = n0 + chn * 8;
                const size_t dst = (size_t)(o >> 4) * 49152 + (size_t)(j >> 5) * 2048 +
                                   s * 512 + ((((j >> 3) & 3) * 16 + (o & 15)) << 3);
                *(bf16x8*)((__bf16*)Cv + dst) = v;
            }
        }
    }
    (void)D2;
}

// ---------------------------------------------------------------------------
// convx (byte-identical to R14): bc[t,o] = sum_s sum_j V[s][o][j]*xbp[t+s][j].
// R8 conv structure, K=768/shift (24 k-iters); B-frags global->register from
// WBf [nt][kcI<24][s][lane][8]; A-halo (132x32) LDS dbuf; 64 MFMA/wave per
// barrier-pair; vmcnt(16); 2 blocks/CU.
// ---------------------------------------------------------------------------
__global__ __launch_bounds__(256, 2)
void convx_mfma(const __hip_bfloat16* __restrict__ xbp,
                const __hip_bfloat16* __restrict__ WBf,
                __hip_bfloat16* __restrict__ C)
{
    __shared__ __align__(16) unsigned char smem[32768];
    __bf16* Ah = (__bf16*)smem;             // [2][132*32] halo dbuf (16.9KB)

    const int tid  = threadIdx.x;
    const int lane = tid & 63;
    const int wave = tid >> 6;
    const size_t m0 = (size_t)blockIdx.x * 128;
    const int    n0 = blockIdx.y * 128;
    const int wm = (wave >> 1) * 64;
    const int wn = (wave & 1) * 64;

    f32x4 acc[4][4];
#pragma unroll
    for (int i = 0; i < 4; ++i)
#pragma unroll
        for (int j = 0; j < 4; ++j)
            acc[i][j] = f32x4{0.f, 0.f, 0.f, 0.f};

    const int frow = lane & 15;
    const int fq   = lane >> 4;

    const __bf16* wbase = (const __bf16*)WBf +
        (size_t)((n0 + wn) >> 4) * 49152 + (lane << 3);

    auto loadB = [&](bf16x8 (&b)[4][4], int t1) {
#pragma unroll
        for (int s = 0; s < 4; ++s)
#pragma unroll
            for (int ni = 0; ni < 4; ++ni)
                b[s][ni] = *(const bf16x8*)(wbase + (size_t)ni * 49152 +
                                            t1 * 2048 + s * 512);
    };
    auto stageA = [&](int abuf, int kc) {   // 132 rows x 4 chunks = 528 chunks
#pragma unroll
        for (int q = 0; q < 2; ++q) {
            const int lin = q * 256 + tid;
            const int rr  = lin >> 2;
            const int gc  = (lin & 3) ^ ((rr >> 1) & 3);
            cp16_g2l(xbp + (m0 + rr) * 768 + kc + gc * 8, Ah + abuf * 4224 + lin * 8);
        }
        if (tid < 16) {
            const int lin = 512 + tid;
            const int rr  = lin >> 2;
            const int gc  = (lin & 3) ^ ((rr >> 1) & 3);
            cp16_g2l(xbp + (m0 + rr) * 768 + kc + gc * 8, Ah + abuf * 4224 + lin * 8);
        }
    };

    bf16x8 bA[4][4], bB[4][4];
    stageA(0, 0);
    loadB(bA, 0);

    auto iter = [&](bf16x8 (&bCur)[4][4], bf16x8 (&bNxt)[4][4], int t) {
        if (t + 1 < 24) {
            loadB(bNxt, t + 1);
            asm volatile("s_waitcnt vmcnt(16)" ::: "memory");
        } else {
            asm volatile("s_waitcnt vmcnt(0)" ::: "memory");
        }
        __builtin_amdgcn_sched_barrier(0);
        __builtin_amdgcn_s_barrier();          // halo[t&1] staged for all waves
        __builtin_amdgcn_sched_barrier(0);

        const int ab = (t & 1) * 4224;
        __builtin_amdgcn_s_setprio(1);
#pragma unroll
        for (int s = 0; s < 4; ++s) {
            bf16x8 af[4];
#pragma unroll
            for (int mi = 0; mi < 4; ++mi) {
                const int R = wm + mi * 16 + frow + s;       // shifted halo row
                af[mi] = *(const bf16x8*)&Ah[ab + R * 32 + ((fq ^ ((R >> 1) & 3)) * 8)];
            }
#pragma unroll
            for (int mi = 0; mi < 4; ++mi)
#pragma unroll
                for (int ni = 0; ni < 4; ++ni)
                    acc[mi][ni] = __builtin_amdgcn_mfma_f32_16x16x32_bf16(
                        af[mi], bCur[s][ni], acc[mi][ni], 0, 0, 0);
        }
        __builtin_amdgcn_s_setprio(0);
        __builtin_amdgcn_sched_barrier(0);
        __builtin_amdgcn_s_barrier();          // halo[t&1] free for overwrite
        __builtin_amdgcn_sched_barrier(0);
        if (t + 1 < 24) stageA((t + 1) & 1, (t + 1) * 32);
    };

#pragma unroll 1
    for (int tp = 0; tp < 12; ++tp) {
        iter(bA, bB, 2 * tp);
        iter(bB, bA, 2 * tp + 1);
    }

    // ---- epilogue: bf16 tile 128x128 via swizzled LDS, coalesced stores.
    __syncthreads();
    const int er = fq * 4;
    const int ec = frow;
    __bf16* Cl = (__bf16*)smem;
#pragma unroll
    for (int ni = 0; ni < 4; ++ni) {
        const int cc = wn + ni * 16 + ec;
#pragma unroll
        for (int mi = 0; mi < 4; ++mi)
#pragma unroll
            for (int r2 = 0; r2 < 4; ++r2) {
                const int R = wm + mi * 16 + er + r2;
                Cl[R * 128 + ((((cc >> 3) ^ (R & 7)) << 3) | (cc & 7))] =
                    f2b(acc[mi][ni][r2]);
            }
    }
    __syncthreads();
#pragma unroll
    for (int p = 0; p < 8; ++p) {
        const int R   = (tid >> 4) + p * 16;
        const int chn = tid & 15;
        const bf16x8 v = *(const bf16x8*)&Cl[R * 128 + ((chn ^ (R & 7)) << 3)];
        *(bf16x8*)((__bf16*)C + (m0 + R) * 1024 + n0 + chn * 8) = v;
    }
}

// ---------------------------------------------------------------------------
// prep1 (byte-identical to R14): xbp (3 zero rows) + w1f (gelu half) +
// w1bT (Vgemm B) + cwr (Vgemm A) + w_rgf + w_outf.
// ---------------------------------------------------------------------------
#define P_XBP  6293760              // 8195*768
#define P_W1F  (P_XBP + 786432)     // 64nt * 24kt * 512
#define P_W1BT (P_W1F + 786432)     // 48nt * 32kt * 512
#define P_CWR  (P_W1BT + 4194304)   // 4096*1024
#define P_WRG  (P_CWR + 2097152)    // 128nt * 32kt * 512
#define P_WO   (P_WRG + 786432)     // 48nt * 32kt * 512
#define P_TOT  P_WO                 // 14,944,512 = 256 * 58377
__global__ void prep1_kernel(const float* __restrict__ x, const float* __restrict__ w1,
                             const float* __restrict__ w_rg, const float* __restrict__ w_out,
                             const float* __restrict__ conv_w,
                             __hip_bfloat16* __restrict__ xbp, __hip_bfloat16* __restrict__ w1f,
                             __hip_bfloat16* __restrict__ w1bT, __hip_bfloat16* __restrict__ cwr,
                             __hip_bfloat16* __restrict__ w_rgf, __hip_bfloat16* __restrict__ w_outf)
{
    const int idx = blockIdx.x * 256 + threadIdx.x;
    if (idx < P_XBP) {
        xbp[idx] = (idx < 2304) ? __float2bfloat16(0.f)
                                : __float2bfloat16(x[idx - 2304]);
    } else if (idx < P_W1F) {
        const int i  = idx - P_XBP;
        const int nti = i / 12288;
        const int r  = i % 12288;
        const int kt = r >> 9;
        const int r2 = r & 511;
        const int l  = r2 >> 3, j0 = r2 & 7;
        const int row = nti * 16 + (l & 15);
        const int col = kt * 32 + (l >> 4) * 8 + j0;
        w1f[i] = __float2bfloat16(w1[row * 768 + col]);
    } else if (idx < P_W1BT) {
        const int i  = idx - P_W1F;
        const int nti = i >> 14;
        const int r  = i & 16383;
        const int kt = r >> 9;
        const int r2 = r & 511;
        const int l  = r2 >> 3, j0 = r2 & 7;
        const int j  = nti * 16 + (l & 15);
        const int k  = kt * 32 + (l >> 4) * 8 + j0;
        w1bT[i] = __float2bfloat16(w1[(1024 + k) * 768 + j]);
    } else if (idx < P_CWR) {
        const int n   = idx - P_W1BT;
        const int row = n >> 10;
        const int i   = n & 1023;
        const int s   = row >> 10;
        const int o   = row & 1023;
        cwr[n] = __float2bfloat16(conv_w[o * 4096 + i * 4 + s]);
    } else if (idx < P_WRG) {
        const int i  = idx - P_CWR;
        const int nti = i >> 14;
        const int r  = i & 16383;
        const int kt = r >> 9;
        const int r2 = r & 511;
        const int l  = r2 >> 3, j0 = r2 & 7;
        const int row = nti * 16 + (l & 15);
        const int col = kt * 32 + (l >> 4) * 8 + j0;
        w_rgf[i] = __float2bfloat16(w_rg[row * 1024 + col]);
    } else {
        const int i  = idx - P_WRG;
        const int nti = i >> 14;
        const int r  = i & 16383;
        const int kt = r >> 9;
        const int r2 = r & 511;
        const int l  = r2 >> 3, j0 = r2 & 7;
        const int row = nti * 16 + (l & 15);
        const int col = kt * 32 + (l >> 4) * 8 + j0;
        w_outf[i] = __float2bfloat16(w_out[row * 1024 + col]);
    }
}

// Gates recomputed inline from g_pre (T x 2048 bf16) + bc (bf16):
__global__ void scan_pass1(const __hip_bfloat16* __restrict__ gp,
                           const __hip_bfloat16* __restrict__ bc,
                           const float* __restrict__ Lambda,
                           float* __restrict__ ch, float* __restrict__ ca)
{
    const int c = blockIdx.y * 256 + threadIdx.x;
    const int j = blockIdx.x;
    const float cl = -8.f * log1pf(expf(Lambda[c]));
    float h = 0.f, ap = 1.f;
    const int t0 = j * CL;
    for (int tt = 0; tt < CL; ++tt) {
        const int t = t0 + tt;
        const long gi = (long)t * 2048 + c;
        const float ig = 1.f / (1.f + expf(-__bfloat162float(gp[gi])));
        const float rg = 1.f / (1.f + expf(-__bfloat162float(gp[gi + 1024])));
        const float a  = expf(cl * rg);
        const float gx = sqrtf(fmaxf(0.f, 1.f - a * a)) * ig *
                         __bfloat162float(bc[(long)t * 1024 + c]);
        h  = fmaf(a, h, gx);
        ap *= a;
    }
    ch[j * 1024 + c] = h;
    ca[j * 1024 + c] = ap;
}

__global__ void scan_combine(float* __restrict__ ch, const float* __restrict__ ca)
{
    const int c = blockIdx.x * 256 + threadIdx.x;
    float carry = 0.f;
    for (int j = 0; j < NC; ++j) {
        const float hj = ch[j * 1024 + c];
        const float aj = ca[j * 1024 + c];
        ch[j * 1024 + c] = carry;
        carry = fmaf(aj, carry, hj);
    }
}

// Rescan with carry; z = ab * y -> bf16 (zb aliases bc: same-element RMW per thread).
__global__ void scan_pass2(const __hip_bfloat16* __restrict__ gp, const __hip_bfloat16* bc,
                           const float* __restrict__ Lambda,
                           const float* __restrict__ carry_in,
                           const __hip_bfloat16* __restrict__ ab,
                           __hip_bfloat16* zb)
{
    const int c = blockIdx.y * 256 + threadIdx.x;
    const int j = blockIdx.x;
    const float cl = -8.f * log1pf(expf(Lambda[c]));
    float h = carry_in[j * 1024 + c];
    const int t0 = j * CL;
    for (int tt = 0; tt < CL; ++tt) {
        const int t = t0 + tt;
        const long gi = (long)t * 2048 + c;
        const long bi = (long)t * 1024 + c;
        const float ig = 1.f / (1.f + expf(-__bfloat162float(gp[gi])));
        const float rg = 1.f / (1.f + expf(-__bfloat162float(gp[gi + 1024])));
        const float a  = expf(cl * rg);
        const float gx = sqrtf(fmaxf(0.f, 1.f - a * a)) * ig * __bfloat162float(bc[bi]);
        h = fmaf(a, h, gx);
        zb[bi] = __float2bfloat16(__bfloat162float(ab[bi]) * h);
    }
}

extern "C" void kernel_launch(void* const* d_in, const int* in_sizes, int n_in,
                              void* d_out, int out_size, void* d_ws, size_t ws_size,
                              hipStream_t stream)
{
    const float* x      = (const float*)d_in[0];
    const float* w1     = (const float*)d_in[1];
    const float* b1     = (const float*)d_in[2];
    const float* conv_w = (const float*)d_in[3];
    const float* w_rg   = (const float*)d_in[4];
    const float* b_rg   = (const float*)d_in[5];
    const float* w_out  = (const float*)d_in[6];
    const float* b_out  = (const float*)d_in[7];
    const float* Lambda = (const float*)d_in[8];
    float* out = (float*)d_out;
    (void)in_sizes; (void)n_in; (void)out_size; (void)ws_size;

    // ---- workspace layout (~105 MB) ----
    char* p = (char*)d_ws;
    auto alloc = [&](size_t bytes) { char* r = p; p += (bytes + 255) & ~255ULL; return r; };
    __hip_bfloat16* gpre  = (__hip_bfloat16*)alloc(8192ULL * 2048 * 2); // 32 MB
    __hip_bfloat16* ab    = (__hip_bfloat16*)alloc(8192ULL * 1024 * 2); // 16 MB
    __hip_bfloat16* xbp   = (__hip_bfloat16*)alloc(8200ULL * 768 * 2);  // 12.6 MB
    __hip_bfloat16* bcb   = (__hip_bfloat16*)alloc(8192ULL * 1024 * 2); // 16 MB (later zb)
    __hip_bfloat16* WBf   = (__hip_bfloat16*)alloc(1024ULL * 4 * 768 * 2); // 6.3 MB
    __hip_bfloat16* cwr   = (__hip_bfloat16*)alloc(4096ULL * 1024 * 2); // 8.4 MB
    __hip_bfloat16* w1f   = (__hip_bfloat16*)alloc(1024ULL * 768 * 2);  // 1.5 MB
    __hip_bfloat16* w1bT  = (__hip_bfloat16*)alloc(768ULL * 1024 * 2);  // 1.5 MB
    __hip_bfloat16* w_rgf = (__hip_bfloat16*)alloc(2048ULL * 1024 * 2); // 4 MB
    __hip_bfloat16* w_outf= (__hip_bfloat16*)alloc(768ULL * 1024 * 2);  // 1.5 MB
    float*          chv   = (float*)alloc(NC * 1024ULL * 4);            // 1 MB
    float*          cav   = (float*)alloc(NC * 1024ULL * 4);            // 1 MB
    __hip_bfloat16* zb    = bcb;   // overlay

    prep1_kernel<<<P_TOT / 256, 256, 0, stream>>>(x, w1, w_rg, w_out, conv_w,
                                                  xbp, w1f, w1bT, cwr, w_rgf, w_outf);

    // V = conv_w (*) w1b, written DIRECTLY into conv frag-major WBf (EPI=3)
    {
        dim3 grid(4096 / 128, 768 / 64);
        gemm_mfma<3><<<grid, 256, 0, stream>>>(cwr, w1bT, nullptr, WBf, 1024, 1024, 768, nullptr);
    }

    // ab = bf16(gelu(x @ w1a.T + b1a))  (gelu half only, N=1024)
    {
        dim3 grid(T_LEN / 128, 1024 / 64);
        gemm_mfma<2><<<grid, 256, 0, stream>>>(xbp + 2304, w1f, b1, ab, DM, DM, 1024, nullptr);
    }

    // bc = sum_s V_s @ x[t+s-3]  (conv directly from padded x)
    {
        dim3 grid(T_LEN / 128, 1024 / 128);
        convx_mfma<<<grid, 256, 0, stream>>>(xbp, WBf, bcb);
    }

    // g_pre = bc @ w_rg.T + b_rg -> bf16
    {
        dim3 grid(T_LEN / 128, 2048 / 64);
        gemm_mfma<1><<<grid, 256, 0, stream>>>(bcb, w_rgf, b_rg, gpre, DR, DR, 2048, nullptr);
    }

    // chunked scan with fused gates; z = ab*y -> bf16 (overlays bcb)
    {
        dim3 gs(NC, DR / 256);
        scan_pass1<<<gs, 256, 0, stream>>>(gpre, bcb, Lambda, chv, cav);
        scan_combine<<<DR / 256, 256, 0, stream>>>(chv, cav);
        scan_pass2<<<gs, 256, 0, stream>>>(gpre, bcb, Lambda, chv, ab, zb);
    }

    // out = z @ w_out.T + b_out -> fp32
    {
        dim3 grid(T_LEN / 128, DM / 64);
        gemm_mfma<0><<<grid, 256, 0, stream>>>(zb, w_outf, b_out, out, DR, DR, DM, nullptr);
    }
}